// Round 2
// baseline (650.409 us; speedup 1.0000x reference)
//
#include <hip/hip_runtime.h>
#include <math.h>

// Problem constants
#define NB 32
#define NC 64          // CODE_DIM
#define NK 2048
#define NCODES 1024
#define NVEC (NB*NK)          // 65536 vectors
#define NELEM (NB*NC*NK)      // 4194304 elements
#define QBLK 2048             // blocks for quant kernel

// ws layout (bytes)
#define WS_CODES 0            // int[NVEC]     = 262144 B
#define WS_HIST  262144       // int[NCODES]   = 4096 B
#define WS_CBN32 266240       // float[NCODES] = 4096 B
#define WS_PART  278528       // double[QBLK]  = 16384 B

// numpy pairwise_sum for n=64 (scalar 8-accumulator pattern), on pre-rounded
// squares q[c] = fl(x[c]*x[c]). Bit-exact vs np.sum(x*x, axis=1) float32.
__device__ __forceinline__ float np_sumsq64(const float* q) {
    float r0 = q[0], r1 = q[1], r2 = q[2], r3 = q[3];
    float r4 = q[4], r5 = q[5], r6 = q[6], r7 = q[7];
#pragma unroll
    for (int i = 8; i < 64; i += 8) {
        r0 = __fadd_rn(r0, q[i + 0]); r1 = __fadd_rn(r1, q[i + 1]);
        r2 = __fadd_rn(r2, q[i + 2]); r3 = __fadd_rn(r3, q[i + 3]);
        r4 = __fadd_rn(r4, q[i + 4]); r5 = __fadd_rn(r5, q[i + 5]);
        r6 = __fadd_rn(r6, q[i + 6]); r7 = __fadd_rn(r7, q[i + 7]);
    }
    float s01 = __fadd_rn(r0, r1), s23 = __fadd_rn(r2, r3);
    float s45 = __fadd_rn(r4, r5), s67 = __fadd_rn(r6, r7);
    return __fadd_rn(__fadd_rn(s01, s23), __fadd_rn(s45, s67));
}

// --- codebook squared norms, numpy-exact fp32 -------------------------------
__global__ void k_cbnorm(const float* __restrict__ cb, float* __restrict__ n32) {
    int j = blockIdx.x * 64 + threadIdx.x;   // 16 x 64 = 1024
    const float* cr = cb + (size_t)j * NC;
    float q[NC];
#pragma unroll
    for (int c = 0; c < NC; c++) q[c] = __fmul_rn(cr[c], cr[c]);
    n32[j] = np_sumsq64(q);
}

// --- argmin over codes: bit-exact replica of np fp32 dist + first-index -----
__launch_bounds__(256)
__global__ void k_argmin(const float* __restrict__ ze, const float* __restrict__ cb,
                         const float* __restrict__ n32,
                         int* __restrict__ codes, int* __restrict__ hist,
                         float* __restrict__ codes_f) {
    int n = blockIdx.x * 256 + threadIdx.x;  // vector id = b*2048 + k
    int b = n >> 11;
    int k = n & (NK - 1);
    const float* zp = ze + (size_t)b * NC * NK + k;
    float z[NC];
#pragma unroll
    for (int c = 0; c < NC; c++) z[c] = zp[(size_t)c * NK];  // coalesced across wave

    // t1 = np.sum(z*z) with numpy's exact rounding
    float q[NC];
#pragma unroll
    for (int c = 0; c < NC; c++) q[c] = __fmul_rn(z[c], z[c]);
    float t1 = np_sumsq64(q);

    float best = 3.0e38f;
    int bidx = 0;
    for (int j = 0; j < NCODES; j += 4) {
        const float* cr = cb + (size_t)j * NC;   // wave-uniform -> scalar loads
        // BLAS sgemm micro-kernel: sequential single-accumulator FMA over k
        float a0 = 0.f, a1 = 0.f, a2 = 0.f, a3 = 0.f;
#pragma unroll
        for (int c = 0; c < NC; c++) {
            float zc = z[c];
            a0 = __fmaf_rn(zc, cr[c         ], a0);
            a1 = __fmaf_rn(zc, cr[c +     NC], a1);
            a2 = __fmaf_rn(zc, cr[c + 2 * NC], a2);
            a3 = __fmaf_rn(zc, cr[c + 3 * NC], a3);
        }
        // dist = fl( fl(t1 + t2_j) - 2*dot )   (2*dot exact)
        float d0 = __fsub_rn(__fadd_rn(t1, n32[j + 0]), __fmul_rn(2.f, a0));
        float d1 = __fsub_rn(__fadd_rn(t1, n32[j + 1]), __fmul_rn(2.f, a1));
        float d2 = __fsub_rn(__fadd_rn(t1, n32[j + 2]), __fmul_rn(2.f, a2));
        float d3 = __fsub_rn(__fadd_rn(t1, n32[j + 3]), __fmul_rn(2.f, a3));
        // np.argmin: strict < keeps FIRST minimal index
        if (d0 < best) { best = d0; bidx = j + 0; }
        if (d1 < best) { best = d1; bidx = j + 1; }
        if (d2 < best) { best = d2; bidx = j + 2; }
        if (d3 < best) { best = d3; bidx = j + 3; }
    }

    codes[n] = bidx;
    codes_f[n] = (float)bidx;
    atomicAdd(&hist[bidx], 1);
}

// --- gather z_q, write z_q_st, accumulate fp64 loss partials ----------------
__launch_bounds__(256)
__global__ void k_quant(const float* __restrict__ ze, const float* __restrict__ cb,
                        const int* __restrict__ codes, float* __restrict__ out,
                        double* __restrict__ part) {
    int tid = blockIdx.x * 256 + threadIdx.x;
    double s = 0.0;
#pragma unroll
    for (int it = 0; it < 8; it++) {
        int idx = tid + it * (QBLK * 256);       // covers NELEM, coalesced
        int k  = idx & (NK - 1);
        int bc = idx >> 11;                      // b*64 + c
        int c  = bc & (NC - 1);
        int b  = bc >> 6;
        int n  = (b << 11) | k;
        int code = codes[n];
        float zev = ze[idx];
        float qv = cb[code * NC + c];
        out[idx] = __fadd_rn(zev, __fsub_rn(qv, zev));   // straight-through value
        double d = (double)qv - (double)zev;
        s += d * d;
    }
    // block-reduce s -> part[blockIdx.x]
    for (int off = 32; off; off >>= 1) s += __shfl_down(s, off);
    __shared__ double ls[4];
    int lane = threadIdx.x & 63, wv = threadIdx.x >> 6;
    if (lane == 0) ls[wv] = s;
    __syncthreads();
    if (threadIdx.x == 0) part[blockIdx.x] = ls[0] + ls[1] + ls[2] + ls[3];
}

// --- final scalars: loss_vq and perplexity ----------------------------------
__launch_bounds__(1024)
__global__ void k_final(const double* __restrict__ part, const int* __restrict__ hist,
                        float* __restrict__ out) {
    int t = threadIdx.x;                         // 1024 threads
    double vL = part[t] + part[t + 1024];        // QBLK = 2048 partials
    double p = (double)hist[t] * (1.0 / (double)NVEC);
    double vE = p * log(p + 1e-10);
    for (int off = 32; off; off >>= 1) {
        vL += __shfl_down(vL, off);
        vE += __shfl_down(vE, off);
    }
    __shared__ double lsL[16], lsE[16];
    int lane = t & 63, wv = t >> 6;
    if (lane == 0) { lsL[wv] = vL; lsE[wv] = vE; }
    __syncthreads();
    if (t == 0) {
        double SL = 0.0, SE = 0.0;
        for (int i = 0; i < 16; i++) { SL += lsL[i]; SE += lsE[i]; }
        double loss_cb = SL / (double)NELEM;     // == loss_commit numerically
        out[NELEM + NVEC]     = (float)(loss_cb + 0.25 * loss_cb);
        out[NELEM + NVEC + 1] = (float)exp(-SE);
    }
}

extern "C" void kernel_launch(void* const* d_in, const int* in_sizes, int n_in,
                              void* d_out, int out_size, void* d_ws, size_t ws_size,
                              hipStream_t stream) {
    const float* ze = (const float*)d_in[0];
    const float* cb = (const float*)d_in[1];
    float* out = (float*)d_out;
    char* ws = (char*)d_ws;

    int*    codes = (int*)(ws + WS_CODES);
    int*    hist  = (int*)(ws + WS_HIST);
    float*  n32   = (float*)(ws + WS_CBN32);
    double* part  = (double*)(ws + WS_PART);

    float* zq      = out;                 // (32, 64, 2048)
    float* codes_f = out + NELEM;         // (32, 2048) as float

    hipMemsetAsync(ws + WS_HIST, 0, NCODES * sizeof(int), stream);
    k_cbnorm<<<16, 64, 0, stream>>>(cb, n32);
    k_argmin<<<NVEC / 256, 256, 0, stream>>>(ze, cb, n32, codes, hist, codes_f);
    k_quant<<<QBLK, 256, 0, stream>>>(ze, cb, codes, zq, part);
    k_final<<<1, 1024, 0, stream>>>(part, hist, out);
}

// Round 3
// 225.889 us; speedup vs baseline: 2.8793x; 2.8793x over previous
//
#include <hip/hip_runtime.h>
#include <math.h>

// Problem constants
#define NB 32
#define NC 64          // CODE_DIM
#define NK 2048
#define NCODES 1024
#define NVEC (NB*NK)          // 65536 vectors
#define NELEM (NB*NC*NK)      // 4194304 elements
#define QBLK 2048             // blocks for quant kernel
#define SZ 68                 // padded LDS row stride (floats), %4==0 for float4

// ws layout (bytes)
#define WS_CODES 0            // int[NVEC]     = 262144 B
#define WS_HIST  262144       // int[NCODES]   = 4096 B
#define WS_CBN32 266240       // float[NCODES] = 4096 B
#define WS_PART  278528       // double[QBLK]  = 16384 B

// numpy pairwise_sum for n=64 (scalar 8-accumulator pattern), on pre-rounded
// squares q[c] = fl(x[c]*x[c]). Bit-exact vs np.sum(x*x, axis=1) float32.
// (validated bit-exact in round 2: absmax 0.0)
__device__ __forceinline__ float np_sumsq64_row(const float* x) {
    float r[8];
#pragma unroll
    for (int j = 0; j < 8; j++) r[j] = __fmul_rn(x[j], x[j]);
#pragma unroll
    for (int i = 8; i < 64; i += 8)
#pragma unroll
        for (int j = 0; j < 8; j++)
            r[j] = __fadd_rn(r[j], __fmul_rn(x[i + j], x[i + j]));
    float s01 = __fadd_rn(r[0], r[1]), s23 = __fadd_rn(r[2], r[3]);
    float s45 = __fadd_rn(r[4], r[5]), s67 = __fadd_rn(r[6], r[7]);
    return __fadd_rn(__fadd_rn(s01, s23), __fadd_rn(s45, s67));
}

// --- codebook squared norms, numpy-exact fp32 -------------------------------
__global__ void k_cbnorm(const float* __restrict__ cb, float* __restrict__ n32) {
    int j = blockIdx.x * 64 + threadIdx.x;   // 16 x 64 = 1024
    const float* cr = cb + (size_t)j * NC;
    float x[NC];
#pragma unroll
    for (int c = 0; c < NC; c++) x[c] = cr[c];
    n32[j] = np_sumsq64_row(x);
}

// --- argmin: register-tiled fp32 "GEMM", bit-exact chain + first-index ------
// Block: 256 threads = 16(tx:codes) x 16(ty:vectors). Tile: 64 vectors x 1024
// codes, k=C=64 fully resident. Per-thread 4x4 accumulators; each accumulator
// is a single sequential-c FMA chain (exact BLAS/np replica, same as round 2).
#define FMA4(i, J, COMP) \
    acc[i][J] = __fmaf_rn(zf[i].x, cf0.COMP, acc[i][J]); \
    acc[i][J] = __fmaf_rn(zf[i].y, cf1.COMP, acc[i][J]); \
    acc[i][J] = __fmaf_rn(zf[i].z, cf2.COMP, acc[i][J]); \
    acc[i][J] = __fmaf_rn(zf[i].w, cf3.COMP, acc[i][J]);

__launch_bounds__(256, 4)
__global__ void k_argmin(const float* __restrict__ ze, const float* __restrict__ cb,
                         const float* __restrict__ n32,
                         int* __restrict__ codes, int* __restrict__ hist,
                         float* __restrict__ codes_f) {
    __shared__ float z_lds[64 * SZ];    // [m][c], stride 68: 2-way conflicts only
    __shared__ float cb_lds[64 * SZ];   // [c][n], stride 68: float4 across n
    __shared__ float t1_lds[64];

    const int tid = threadIdx.x;
    const int tx = tid & 15, ty = tid >> 4;
    const int vec0 = blockIdx.x * 64;          // 64 vectors, all in one batch b
    const int b = vec0 >> 11, k0 = vec0 & (NK - 1);
    const float* zbase = ze + (size_t)b * NC * NK + k0;

    // stage z transposed: thread t -> k=t>>2, c=(t&3)+4*pass  (2-way LDS banks)
    {
        const int k = tid >> 2, cb0 = tid & 3;
#pragma unroll
        for (int pass = 0; pass < 16; pass++) {
            int c = cb0 + 4 * pass;
            z_lds[k * SZ + c] = zbase[(size_t)c * NK + k];
        }
    }
    __syncthreads();

    // t1 = np.sum(z*z) per vector, numpy-exact
    if (tid < 64) {
        float x[NC];
#pragma unroll
        for (int c = 0; c < NC; c++) x[c] = z_lds[tid * SZ + c];
        t1_lds[tid] = np_sumsq64_row(x);
    }
    __syncthreads();

    float t1[4];
#pragma unroll
    for (int i = 0; i < 4; i++) t1[i] = t1_lds[ty * 4 + i];

    float best[4] = {3.0e38f, 3.0e38f, 3.0e38f, 3.0e38f};
    int bidx[4] = {0, 0, 0, 0};

    for (int chunk = 0; chunk < 16; chunk++) {
        __syncthreads();   // previous chunk's readers done before restaging
        // stage 64-code cb chunk transposed to [c][n]
        {
            const int n = tid >> 2;
            const int c4b = (tid & 3) * 4;
            const float* crow = cb + (size_t)(chunk * 64 + n) * NC;
#pragma unroll
            for (int pass = 0; pass < 4; pass++) {
                int c4 = c4b + 16 * pass;
                float4 v = *(const float4*)(crow + c4);
                cb_lds[(c4 + 0) * SZ + n] = v.x;
                cb_lds[(c4 + 1) * SZ + n] = v.y;
                cb_lds[(c4 + 2) * SZ + n] = v.z;
                cb_lds[(c4 + 3) * SZ + n] = v.w;
            }
        }
        __syncthreads();

        float acc[4][4];
#pragma unroll
        for (int i = 0; i < 4; i++)
#pragma unroll
            for (int j = 0; j < 4; j++) acc[i][j] = 0.0f;

#pragma unroll 2
        for (int cc = 0; cc < NC; cc += 4) {
            float4 zf[4];
#pragma unroll
            for (int i = 0; i < 4; i++)
                zf[i] = *(const float4*)&z_lds[(ty * 4 + i) * SZ + cc];
            float4 cf0 = *(const float4*)&cb_lds[(cc + 0) * SZ + tx * 4];
            float4 cf1 = *(const float4*)&cb_lds[(cc + 1) * SZ + tx * 4];
            float4 cf2 = *(const float4*)&cb_lds[(cc + 2) * SZ + tx * 4];
            float4 cf3 = *(const float4*)&cb_lds[(cc + 3) * SZ + tx * 4];
#pragma unroll
            for (int i = 0; i < 4; i++) {
                FMA4(i, 0, x)
                FMA4(i, 1, y)
                FMA4(i, 2, z)
                FMA4(i, 3, w)
            }
        }

        // dist = fl( fl(t1 + t2_n) - 2*dot ), strict < keeps FIRST index
        const int nbase = chunk * 64 + tx * 4;
        float4 n2v = *(const float4*)&n32[nbase];
#pragma unroll
        for (int i = 0; i < 4; i++) {
            float d0 = __fsub_rn(__fadd_rn(t1[i], n2v.x), __fmul_rn(2.f, acc[i][0]));
            float d1 = __fsub_rn(__fadd_rn(t1[i], n2v.y), __fmul_rn(2.f, acc[i][1]));
            float d2 = __fsub_rn(__fadd_rn(t1[i], n2v.z), __fmul_rn(2.f, acc[i][2]));
            float d3 = __fsub_rn(__fadd_rn(t1[i], n2v.w), __fmul_rn(2.f, acc[i][3]));
            if (d0 < best[i]) { best[i] = d0; bidx[i] = nbase + 0; }
            if (d1 < best[i]) { best[i] = d1; bidx[i] = nbase + 1; }
            if (d2 < best[i]) { best[i] = d2; bidx[i] = nbase + 2; }
            if (d3 < best[i]) { best[i] = d3; bidx[i] = nbase + 3; }
        }
    }

    // cross-tx reduction: key = (dist_bits<<32)|idx; dist>0 so bit-monotone;
    // min key == min dist, tie -> min idx (numpy first-index rule)
    __syncthreads();
    unsigned long long* keys = (unsigned long long*)cb_lds;  // 64*16*8 = 8 KB
#pragma unroll
    for (int i = 0; i < 4; i++) {
        unsigned int db = __float_as_uint(best[i]);
        keys[(ty * 4 + i) * 16 + tx] = ((unsigned long long)db << 32) | (unsigned int)bidx[i];
    }
    __syncthreads();
    if (tid < 64) {
        unsigned long long kmin = keys[tid * 16];
#pragma unroll
        for (int t = 1; t < 16; t++) {
            unsigned long long kk = keys[tid * 16 + t];
            if (kk < kmin) kmin = kk;
        }
        int code = (int)(kmin & 0xFFFFFFFFu);
        int n = vec0 + tid;
        codes[n] = code;
        codes_f[n] = (float)code;
        atomicAdd(&hist[code], 1);
    }
}

// --- gather z_q, write z_q_st, accumulate fp64 loss partials ----------------
__launch_bounds__(256)
__global__ void k_quant(const float* __restrict__ ze, const float* __restrict__ cb,
                        const int* __restrict__ codes, float* __restrict__ out,
                        double* __restrict__ part) {
    int tid = blockIdx.x * 256 + threadIdx.x;
    double s = 0.0;
#pragma unroll
    for (int it = 0; it < 8; it++) {
        int idx = tid + it * (QBLK * 256);       // covers NELEM, coalesced
        int k  = idx & (NK - 1);
        int bc = idx >> 11;                      // b*64 + c
        int c  = bc & (NC - 1);
        int b  = bc >> 6;
        int n  = (b << 11) | k;
        int code = codes[n];
        float zev = ze[idx];
        float qv = cb[code * NC + c];
        out[idx] = __fadd_rn(zev, __fsub_rn(qv, zev));   // straight-through value
        double d = (double)qv - (double)zev;
        s += d * d;
    }
    // block-reduce s -> part[blockIdx.x]
    for (int off = 32; off; off >>= 1) s += __shfl_down(s, off);
    __shared__ double ls[4];
    int lane = threadIdx.x & 63, wv = threadIdx.x >> 6;
    if (lane == 0) ls[wv] = s;
    __syncthreads();
    if (threadIdx.x == 0) part[blockIdx.x] = ls[0] + ls[1] + ls[2] + ls[3];
}

// --- final scalars: loss_vq and perplexity ----------------------------------
__launch_bounds__(1024)
__global__ void k_final(const double* __restrict__ part, const int* __restrict__ hist,
                        float* __restrict__ out) {
    int t = threadIdx.x;                         // 1024 threads
    double vL = part[t] + part[t + 1024];        // QBLK = 2048 partials
    double p = (double)hist[t] * (1.0 / (double)NVEC);
    double vE = p * log(p + 1e-10);
    for (int off = 32; off; off >>= 1) {
        vL += __shfl_down(vL, off);
        vE += __shfl_down(vE, off);
    }
    __shared__ double lsL[16], lsE[16];
    int lane = t & 63, wv = t >> 6;
    if (lane == 0) { lsL[wv] = vL; lsE[wv] = vE; }
    __syncthreads();
    if (t == 0) {
        double SL = 0.0, SE = 0.0;
        for (int i = 0; i < 16; i++) { SL += lsL[i]; SE += lsE[i]; }
        double loss_cb = SL / (double)NELEM;     // == loss_commit numerically
        out[NELEM + NVEC]     = (float)(loss_cb + 0.25 * loss_cb);
        out[NELEM + NVEC + 1] = (float)exp(-SE);
    }
}

extern "C" void kernel_launch(void* const* d_in, const int* in_sizes, int n_in,
                              void* d_out, int out_size, void* d_ws, size_t ws_size,
                              hipStream_t stream) {
    const float* ze = (const float*)d_in[0];
    const float* cb = (const float*)d_in[1];
    float* out = (float*)d_out;
    char* ws = (char*)d_ws;

    int*    codes = (int*)(ws + WS_CODES);
    int*    hist  = (int*)(ws + WS_HIST);
    float*  n32   = (float*)(ws + WS_CBN32);
    double* part  = (double*)(ws + WS_PART);

    float* zq      = out;                 // (32, 64, 2048)
    float* codes_f = out + NELEM;         // (32, 2048) as float

    hipMemsetAsync(ws + WS_HIST, 0, NCODES * sizeof(int), stream);
    k_cbnorm<<<16, 64, 0, stream>>>(cb, n32);
    k_argmin<<<NVEC / 64, 256, 0, stream>>>(ze, cb, n32, codes, hist, codes_f);
    k_quant<<<QBLK, 256, 0, stream>>>(ze, cb, codes, zq, part);
    k_final<<<1, 1024, 0, stream>>>(part, hist, out);
}